// Round 3
// baseline (28446.194 us; speedup 1.0000x reference)
//
#include <hip/hip_runtime.h>

// ---------------- problem constants ----------------
#define T_SEQ 8192
#define HDIM  256
#define VOC   28
#define LAT   32
#define CDIM  8

// ---------------- decomposition ----------------
#define NWG   16      // workgroups; WG w owns h[k] for k in [w*16, w*16+16)
#define NTHR  512     // 8 waves/WG; wave v owns k = w*16 + 2v, +2v+1 (full rows)
#define SEGW  36      // padded LDS stride per 32-elem h segment (bank-conflict-free:
                      // element e lives at hp[(e>>5)*SEGW + (e&31)]; segment s starts
                      // at bank 4s, so the 8 segment-readers never collide)

#define OUT_PRED (T_SEQ)
#define OUT_MEAN (T_SEQ + T_SEQ*VOC)
#define OUT_LV   (OUT_MEAN + LAT)

__device__ __forceinline__ float sigm(float x){
  x = fminf(fmaxf(x, -30.f), 30.f);
  return 1.f/(1.f + __expf(-x));
}
__device__ __forceinline__ float tanhfast(float x){
  x = fminf(fmaxf(x, -15.f), 15.f);
  float e = __expf(2.f*x);
  return (e-1.f)/(e+1.f);
}

// Persistent kernel: 16 WGs run both LSTM scans; h exchanged per step via the
// PROVEN packed (tag<<32|h) 8B agent-scope atomics, 2-parity buffer. Each wave
// computes 8 full gate rows (8 lanes/row) -> in-wave shfl reduce -> gates for
// its 2 h-elements -> publish. ONE barrier per step, no LDS partial buffer.
__global__ __launch_bounds__(NTHR, 1)
void cvae_persist(
    const int* __restrict__ input, const int* __restrict__ tense_p, const float* __restrict__ eps,
    const float* __restrict__ enc_embed, const float* __restrict__ enc_wih, const float* __restrict__ enc_whh,
    const float* __restrict__ enc_bih, const float* __restrict__ enc_bhh,
    const float* __restrict__ dec_embed, const float* __restrict__ dec_wih, const float* __restrict__ dec_whh,
    const float* __restrict__ dec_bih, const float* __restrict__ dec_bhh,
    const float* __restrict__ h2m_w, const float* __restrict__ h2m_b,
    const float* __restrict__ h2v_w, const float* __restrict__ h2v_b,
    const float* __restrict__ cond_embed, const float* __restrict__ lat2emb_w, const float* __restrict__ lat2emb_b,
    float* __restrict__ d_out, unsigned long long* __restrict__ hb, float* __restrict__ hs)
{
  __shared__ __align__(16) float hlds[2][8*SEGW];  // 2-parity padded h
  __shared__ float tbl[2][VOC*64];                 // per-vocab input-gate tables
  __shared__ unsigned char toks[T_SEQ];
  __shared__ float pbuf[64*9];                     // init/middle phases only
  __shared__ float lat[LAT+CDIM];

  const int w   = blockIdx.x;
  const int tid = threadIdx.x;
  const int v   = tid >> 6;            // wave id 0..7
  const int lam = tid & 63;            // lane
  const int j   = lam >> 3;            // row-slot 0..7 within wave
  const int s   = lam & 7;             // col-segment 0..7 (32 cols each)
  const int gate= j & 3;               // 0=i 1=f 2=g 3=o (PyTorch order)
  const int kloc= v*2 + (j >> 2);      // local h index 0..15
  const int k   = (w<<4) + kloc;       // global h index this lane's row feeds
  const int R   = gate*256 + k;        // global gate-row
  const int rho = gate*16 + kloc;      // local row id for tbl

  // ---- token list into LDS ----
  for (int i = tid; i < T_SEQ; i += NTHR) toks[i] = (unsigned char)input[i];

  // ---- per-vocab input tables: tbl[ph][v*64+rho] = Wih[Rb,:]@x_v + bih+bhh ----
  {
    const int rb  = lam;                               // build-row 0..63
    const int cb  = v;                                 // build-chunk 0..7
    const int Rb  = (rb>>4)*256 + (w<<4) + (rb&15);
    float wtmp[32];
    for (int ph = 0; ph < 2; ++ph){
      const float* wih = ph ? dec_wih   : enc_wih;
      const float* emb = ph ? dec_embed : enc_embed;
      const float* bih = ph ? dec_bih   : enc_bih;
      const float* bhh = ph ? dec_bhh   : enc_bhh;
      #pragma unroll
      for (int i = 0; i < 32; ++i) wtmp[i] = wih[(size_t)Rb*HDIM + cb*32 + i];
      #pragma unroll 1
      for (int vv = 0; vv < VOC; ++vv){
        float p = 0.f;
        const float* xr = emb + vv*HDIM + cb*32;
        #pragma unroll
        for (int i = 0; i < 32; ++i){
          float x = xr[i];
          if (ph) x = fmaxf(x, 0.f);                   // decoder: relu(embed)
          p += wtmp[i]*x;
        }
        pbuf[rb*9 + cb] = p;
        __syncthreads();
        if (tid < 64){
          float sm = 0.f;
          #pragma unroll
          for (int q = 0; q < 8; ++q) sm += pbuf[tid*9 + q];
          const int Rt = (tid>>4)*256 + (w<<4) + (tid&15);
          tbl[ph][vv*64 + tid] = sm + bih[Rt] + bhh[Rt];
        }
        __syncthreads();
      }
    }
  }

  // ---- recurrent weight slices -> VGPRs (this lane's row R, segment s) ----
  float wenc[32], wdec[32];
  #pragma unroll
  for (int i = 0; i < 32; ++i){
    wenc[i] = enc_whh[(size_t)R*HDIM + s*32 + i];
    wdec[i] = dec_whh[(size_t)R*HDIM + s*32 + i];
  }

  // ---- encoder init: h0 = [0...; cond] into parity-0 padded buffer ----
  const int tense = tense_p[0];
  if (tid < HDIM){
    float x = (tid >= HDIM-CDIM) ? cond_embed[tense*CDIM + (tid-(HDIM-CDIM))] : 0.f;
    hlds[0][(tid>>5)*SEGW + (tid&31)] = x;
  }
  float cst = 0.f;                       // cell state (replicated per 32-lane k-group)
  int budget = 8000000;                  // spin valve: bug -> wrong answer, not hang
  __syncthreads();

  // ---- one LSTM step (tag t; reads hlds[(t&1)^1], writes hlds[t&1]) ----
  auto step = [&](int t, const float (&wv)[32], int tok, int isdec, int srow){
    const float* hp_r = hlds[(t&1)^1];
    float*       hp_w = hlds[t&1];

    // matvec: 8 lanes per row, 32 cols each, padded-LDS float4 reads
    float p = 0.f;
    {
      const float4* h4 = (const float4*)(hp_r + s*SEGW);
      #pragma unroll
      for (int m = 0; m < 8; ++m){
        float4 hh = h4[m];
        p += wv[4*m+0]*hh.x + wv[4*m+1]*hh.y
           + wv[4*m+2]*hh.z + wv[4*m+3]*hh.w;
      }
    }
    // in-wave 8-lane row reduce (stays within each row's 8-lane group)
    p += __shfl_xor(p, 1);
    p += __shfl_xor(p, 2);
    p += __shfl_xor(p, 4);
    // add input-table term, activate (i,f,o: sigm; g: tanh)
    float sg = p + tbl[isdec][tok*64 + rho];
    float a  = (gate == 2) ? tanhfast(sg) : sigm(sg);
    // gather 4 gates of this lane's k-group (rows live at base+{0,8,16,24})
    const int base = (lam & 32) + (lam & 7);
    float ai = __shfl(a, base);
    float af = __shfl(a, base + 8);
    float ag = __shfl(a, base + 16);
    float ao = __shfl(a, base + 24);
    float c2 = af*cst + ai*ag;
    float h2 = ao*tanhfast(c2);
    cst = c2;
    // publish own h element (lane 0 of each 32-lane k-group)
    if ((lam & 31) == 0){
      hp_w[(k>>5)*SEGW + (k&31)] = h2;              // own slice direct to LDS
      unsigned long long pr =
          (((unsigned long long)(unsigned int)t) << 32) |
           (unsigned long long)__float_as_uint(h2);
      __hip_atomic_store(&hb[((t&1)<<8) + k], pr,
                         __ATOMIC_RELAXED, __HIP_MEMORY_SCOPE_AGENT);
      if (isdec) hs[(size_t)srow*HDIM + k] = h2;
    }
    // poll: wave v covers slots [v*32, v*32+32), lanes 0..31, skip own WG's
    {
      const int slot  = (v<<5) + (lam & 31);
      const bool act  = (lam < 32);
      const bool own  = ((slot >> 4) == w);
      const unsigned long long* pa = &hb[((t&1)<<8) + slot];
      unsigned long long val = 0;
      for (;;){
        bool ok = true;
        if (act && !own){
          val = __hip_atomic_load(pa, __ATOMIC_RELAXED, __HIP_MEMORY_SCOPE_AGENT);
          ok = ((int)(val >> 32) >= t);
        }
        if (__all(ok)) break;
        if (--budget < 0) break;
      }
      if (act && !own)
        hp_w[(slot>>5)*SEGW + (slot&31)] = __uint_as_float((unsigned int)val);
    }
    __syncthreads();                    // the ONE barrier per step
  };

  // ---- encoder scan: tags 1..T ----
  #pragma unroll 1
  for (int t = 0; t < T_SEQ; ++t)
    step(t+1, wenc, (int)toks[t], 0, 0);

  // ---- middle phase (redundant in every WG). hT is in hlds[0] (T even). ----
  {
    const float* wm = (lam < 32) ? (h2m_w + (size_t)lam*HDIM)
                                 : (h2v_w + (size_t)(lam-32)*HDIM);
    float pm = 0.f;
    #pragma unroll
    for (int i = 0; i < 32; ++i) pm += wm[v*32 + i]*hlds[0][v*SEGW + i];
    pbuf[lam*9 + v] = pm;
    __syncthreads();
    if (v == 0){
      float sm = 0.f;
      #pragma unroll
      for (int q = 0; q < 8; ++q) sm += pbuf[lam*9 + q];
      sm += (lam < 32) ? h2m_b[lam] : h2v_b[lam-32];
      float other = __shfl(sm, (lam&31) + 32);       // lanes<32 fetch log_var
      if (lam < 32){
        float mean = sm, lv = other;
        lat[lam] = eps[lam]*__expf(0.5f*lv) + mean;  // reparameterize
        if (w == 0){
          d_out[OUT_MEAN + lam] = mean;
          d_out[OUT_LV   + lam] = lv;
        }
      }
      if (lam < CDIM) lat[LAT + lam] = cond_embed[tense*CDIM + lam];
    }
    cst = 0.f;                                       // decoder c0 = 0 (all lanes)
    __syncthreads();
    float dh = 0.f;
    if (tid < HDIM){
      dh = lat2emb_b[tid];
      #pragma unroll
      for (int q = 0; q < LAT+CDIM; ++q) dh += lat2emb_w[tid*(LAT+CDIM) + q]*lat[q];
    }
    __syncthreads();
    if (tid < HDIM) hlds[0][(tid>>5)*SEGW + (tid&31)] = dh;  // decoder h0, parity 0
    __syncthreads();
  }

  // ---- decoder scan: tags T+1..2T; teacher forcing tok = [SOS, input[0..T-2]] ----
  #pragma unroll 1
  for (int sd = 0; sd < T_SEQ; ++sd){
    const int tok = sd ? (int)toks[sd-1] : 0;        // SOS = 0
    step(T_SEQ + 1 + sd, wdec, tok, 1, sd);
  }
}

// Output projection + argmax over stored decoder states (fully parallel).
__global__ __launch_bounds__(256, 1)
void cvae_proj(const float* __restrict__ hs, const float* __restrict__ out_w,
               const float* __restrict__ out_b, float* __restrict__ d_out)
{
  __shared__ float ow[VOC*HDIM];   // 28 KB
  __shared__ float ob[VOC];
  const int tid = threadIdx.x;
  for (int i = tid; i < VOC*HDIM; i += 256) ow[i] = out_w[i];
  if (tid < VOC) ob[tid] = out_b[tid];
  __syncthreads();

  const int t = blockIdx.x*256 + tid;
  const float* hr = hs + (size_t)t*HDIM;
  float acc[VOC];
  #pragma unroll
  for (int vv = 0; vv < VOC; ++vv) acc[vv] = ob[vv];
  #pragma unroll 4
  for (int jj = 0; jj < HDIM; jj += 4){
    float4 h4 = *(const float4*)(hr + jj);
    #pragma unroll
    for (int vv = 0; vv < VOC; ++vv){
      acc[vv] += h4.x*ow[vv*HDIM + jj]     + h4.y*ow[vv*HDIM + jj + 1]
               + h4.z*ow[vv*HDIM + jj + 2] + h4.w*ow[vv*HDIM + jj + 3];
    }
  }
  float best = acc[0]; int bi = 0;
  #pragma unroll
  for (int vv = 1; vv < VOC; ++vv){ if (acc[vv] > best){ best = acc[vv]; bi = vv; } }
  float* pd = d_out + OUT_PRED + (size_t)t*VOC;
  #pragma unroll
  for (int vv = 0; vv < VOC; ++vv) pd[vv] = acc[vv];
  d_out[t] = (float)bi;                        // first-occurrence argmax
}

extern "C" void kernel_launch(void* const* d_in, const int* in_sizes, int n_in,
                              void* d_out, int out_size, void* d_ws, size_t ws_size,
                              hipStream_t stream)
{
  const int*   input     = (const int*)  d_in[0];
  const int*   tense     = (const int*)  d_in[1];
  const float* eps       = (const float*)d_in[2];
  const float* enc_embed = (const float*)d_in[3];
  const float* enc_wih   = (const float*)d_in[4];
  const float* enc_whh   = (const float*)d_in[5];
  const float* enc_bih   = (const float*)d_in[6];
  const float* enc_bhh   = (const float*)d_in[7];
  const float* dec_embed = (const float*)d_in[8];
  const float* dec_wih   = (const float*)d_in[9];
  const float* dec_whh   = (const float*)d_in[10];
  const float* dec_bih   = (const float*)d_in[11];
  const float* dec_bhh   = (const float*)d_in[12];
  const float* out_w     = (const float*)d_in[13];
  const float* out_b     = (const float*)d_in[14];
  const float* h2m_w     = (const float*)d_in[15];
  const float* h2m_b     = (const float*)d_in[16];
  const float* h2v_w     = (const float*)d_in[17];
  const float* h2v_b     = (const float*)d_in[18];
  const float* cond_embed= (const float*)d_in[19];
  const float* lat2emb_w = (const float*)d_in[20];
  const float* lat2emb_b = (const float*)d_in[21];

  // ws layout: [512, 4608) (tag,h) exchange: 2 parities x 256 slots x 8B
  //            [8192, +8MB) decoder hidden-state history
  unsigned long long* hb = (unsigned long long*)((char*)d_ws + 512);
  float*              hs = (float*)((char*)d_ws + 8192);

  // Zero exchange tags (d_ws is poisoned 0xAA before every launch).
  hipMemsetAsync(d_ws, 0, 8192, stream);

  hipLaunchKernelGGL(cvae_persist, dim3(NWG), dim3(NTHR), 0, stream,
      input, tense, eps, enc_embed, enc_wih, enc_whh, enc_bih, enc_bhh,
      dec_embed, dec_wih, dec_whh, dec_bih, dec_bhh,
      h2m_w, h2m_b, h2v_w, h2v_b, cond_embed, lat2emb_w, lat2emb_b,
      (float*)d_out, hb, hs);

  hipLaunchKernelGGL(cvae_proj, dim3(T_SEQ/256), dim3(256), 0, stream,
      hs, out_w, out_b, (float*)d_out);
}